// Round 7
// baseline (443.758 us; speedup 1.0000x reference)
//
#include <hip/hip_runtime.h>
#include <cstdint>
#include <cstddef>
#include <math.h>

// RESK GCN forward: 4 graph-conv layers + residuals + log_softmax.
// R7: (1) final-layer support padded to stride 64 bf16 -> aligned 128B rows,
//     2 lines/edge instead of avg 2.25; agg_final gets 8 gather chains.
//     (2) agg64 16 gather chains (VGPR headroom is huge, MLP is the knob).
//     (3) bkt entries 4B payload + 1B row (w->w15 in bucket_kernel), cutting
//     bucket write + rowsort read from 12.8 MB to 8 MB.

typedef unsigned int uint;
typedef unsigned short ushort;
typedef unsigned char uchar;

constexpr int NB_ROWS = 256;   // rows per bucket
constexpr int CHUNK   = 2048;  // edges per bucket_kernel block
constexpr int CAP     = 4608;  // bucket window capacity (mean 4096, +8 sigma)

__device__ __forceinline__ uint f2bf(float f) {
    uint u = __float_as_uint(f);
    return (u + 0x7FFFu + ((u >> 16) & 1u)) >> 16;
}

__global__ void zero_ints(int* __restrict__ p, int n) {
    int i = blockIdx.x * blockDim.x + threadIdx.x;
    if (i < n) p[i] = 0;
}

// Stage 1: bin edges by bucket (tgt>>8) in LDS; write per-(block,bucket) runs
// contiguously. Payload = src | w15<<17 (4B) + row byte (1B side array).
__global__ __launch_bounds__(512) void bucket_kernel(const int* __restrict__ src,
                                                     const int* __restrict__ tgt,
                                                     const float* __restrict__ w,
                                                     int* __restrict__ bcur,
                                                     uint* __restrict__ bkt,
                                                     uchar* __restrict__ brow,
                                                     int E, int NB) {
    __shared__ uint binned[CHUNK];           // 8 KB
    __shared__ ushort binb[CHUNK];           // 4 KB (bucket id)
    __shared__ uchar binr[CHUNK];            // 2 KB (local row)
    __shared__ int hist[512];
    __shared__ int sc[512];
    __shared__ int cur[512];
    __shared__ int gbase[512];
    int tid = threadIdx.x;
    int e0 = blockIdx.x * CHUNK;
    int cnt = min(CHUNK, E - e0);
    hist[tid] = 0;
    __syncthreads();
    for (int i = tid; i < cnt; i += 512) atomicAdd(&hist[tgt[e0 + i] >> 8], 1);
    __syncthreads();
    int v = hist[tid];
    sc[tid] = v;
    __syncthreads();
    for (int off = 1; off < 512; off <<= 1) {
        int t = (tid >= off) ? sc[tid - off] : 0;
        __syncthreads();
        sc[tid] += t;
        __syncthreads();
    }
    int excl = sc[tid] - v;
    if (tid < NB && v > 0) gbase[tid] = atomicAdd(&bcur[tid], v);
    __syncthreads();
    hist[tid] = excl;
    cur[tid] = excl;
    __syncthreads();
    for (int i = tid; i < cnt; i += 512) {
        int t = tgt[e0 + i];
        int b = t >> 8;
        int r = atomicAdd(&cur[b], 1);
        float wf = w[e0 + i];
        uint w15 = (uint)(int)(wf * 32767.f + 0.5f);
        if (w15 > 32767u) w15 = 32767u;
        binned[r] = (uint)src[e0 + i] | (w15 << 17);
        binb[r] = (ushort)b;
        binr[r] = (uchar)(t & 255);
    }
    __syncthreads();
    // bucket-ordered: consecutive threads write consecutive window addresses.
    for (int i = tid; i < cnt; i += 512) {
        int b = binb[i];
        int dst = gbase[b] + (i - hist[b]);
        if (dst < CAP) {
            bkt[(size_t)b * CAP + dst] = binned[i];
            brow[(size_t)b * CAP + dst] = binr[i];
        }
    }
}

// Stage 2: exclusive scan of bucket totals -> bucket bases; total -> row_start[N].
__global__ void bscan_kernel(const int* __restrict__ bcur, int* __restrict__ bbase,
                             int* __restrict__ row_start, int NB, int N) {
    __shared__ int sd[512];
    int tid = threadIdx.x;
    int tot = (tid < NB) ? min(bcur[tid], CAP) : 0;
    sd[tid] = tot;
    __syncthreads();
    for (int off = 1; off < 512; off <<= 1) {
        int t = (tid >= off) ? sd[tid - off] : 0;
        __syncthreads();
        sd[tid] += t;
        __syncthreads();
    }
    if (tid < NB) bbase[tid] = sd[tid] - tot;
    if (tid == 511) row_start[N] = sd[511];
}

// Stage 3: per-bucket row sort -> row_start + row-sorted 4B csr entries.
__global__ __launch_bounds__(1024) void rowsort_kernel(const uint* __restrict__ bkt,
                                                       const uchar* __restrict__ brow,
                                                       const int* __restrict__ bcur,
                                                       const int* __restrict__ bbase,
                                                       uint* __restrict__ csr,
                                                       int* __restrict__ row_start, int N) {
    __shared__ int hist[256];
    __shared__ int offs[256];
    int b = blockIdx.x;
    int tid = threadIdx.x;
    int cnt = min(bcur[b], CAP);
    const uint* win = bkt + (size_t)b * CAP;
    const uchar* wrow = brow + (size_t)b * CAP;
    if (tid < 256) hist[tid] = 0;
    __syncthreads();
    uint en[5];
    uchar er[5];
    int ne = 0;
#pragma unroll
    for (int k = 0; k < 5; ++k) {
        int i = tid + k * 1024;
        if (i < cnt) {
            en[k] = win[i];
            er[k] = wrow[i];
            atomicAdd(&hist[er[k]], 1);
            ne = k + 1;
        }
    }
    __syncthreads();
    int v = 0;
    if (tid < 256) { v = hist[tid]; offs[tid] = v; }
    __syncthreads();
    for (int off = 1; off < 256; off <<= 1) {
        int t = 0;
        if (tid < 256 && tid >= off) t = offs[tid - off];
        __syncthreads();
        if (tid < 256) offs[tid] += t;
        __syncthreads();
    }
    int gb = bbase[b];
    if (tid < 256) {
        int excl = offs[tid] - v;
        int row = (b << 8) + tid;
        if (row < N) row_start[row] = gb + excl;
        hist[tid] = excl;
    }
    __syncthreads();
#pragma unroll
    for (int k = 0; k < 5; ++k) {
        if (k < ne) {
            int pos = atomicAdd(&hist[er[k]], 1);
            csr[gb + pos] = en[k];
        }
    }
}

// support = H @ W, output bf16 with row stride OS (bf16 elems). Wave-split
// columns: block = 64 nodes x WPN waves; wave cg handles C/WPN columns
// (cg wave-uniform -> W reads scalar; H rows L1-reused within block).
template <int K, int C, int WPN, int OS>
__global__ __launch_bounds__(64 * WPN) void gemm_kernel(const float* __restrict__ H,
                                                        const float* __restrict__ W,
                                                        uint* __restrict__ out, int n) {
    constexpr int CW = C / WPN;
    int wave = threadIdx.x >> 6;
    int lane = threadIdx.x & 63;
    int cg = __builtin_amdgcn_readfirstlane(wave);
    int node = blockIdx.x * 64 + lane;
    if (node >= n) return;
    float acc[CW];
#pragma unroll
    for (int c = 0; c < CW; ++c) acc[c] = 0.f;
    const float4* row = (const float4*)(H + (size_t)node * K);
    const float* Wg = W + cg * CW;
#pragma unroll 4
    for (int k4 = 0; k4 < K / 4; ++k4) {
        float4 xv = row[k4];
        const float* wr = Wg + (size_t)k4 * 4 * C;
#pragma unroll
        for (int c = 0; c < CW; ++c) {
            acc[c] = fmaf(xv.x, wr[c], acc[c]);
            acc[c] = fmaf(xv.y, wr[C + c], acc[c]);
            acc[c] = fmaf(xv.z, wr[2 * C + c], acc[c]);
            acc[c] = fmaf(xv.w, wr[3 * C + c], acc[c]);
        }
    }
    uint wbuf[CW / 2];
#pragma unroll
    for (int c = 0; c < CW; c += 2) wbuf[c / 2] = f2bf(acc[c]) | (f2bf(acc[c + 1]) << 16);
    uint* orow = out + (size_t)node * (OS / 2) + cg * (CW / 2);
#pragma unroll
    for (int j = 0; j < CW / 2; ++j) orow[j] = wbuf[j];
}

__device__ __forceinline__ float bfval(const ushort* sb, uint d, int col) {
    return __uint_as_float((uint)sb[(size_t)(d & 0x1FFFF) * 64 + col] << 16);
}
__device__ __forceinline__ float wval(uint d) {
    return (float)(d >> 17) * (1.0f / 32767.f);
}

// Wave-per-node aggregation, C=64: lane = column; 16 independent gather chains.
// out may alias resid (each thread touches only its own element).
__global__ __launch_bounds__(256) void agg64_kernel(const ushort* __restrict__ sb,
                                                    const int* __restrict__ row_start,
                                                    const uint* __restrict__ csr,
                                                    const float* __restrict__ bias,
                                                    const float* __restrict__ resid,
                                                    float* __restrict__ out, int n) {
    int wid = (blockIdx.x * blockDim.x + threadIdx.x) >> 6;
    int lane = threadIdx.x & 63;
    if (wid >= n) return;
    float bv = bias[lane];
    int beg = __builtin_amdgcn_readfirstlane(row_start[wid]);
    int end = __builtin_amdgcn_readfirstlane(row_start[wid + 1]);
    float a[16];
#pragma unroll
    for (int k = 0; k < 16; ++k) a[k] = 0.f;
    int e = beg;
    for (; e + 15 < end; e += 16) {
        uint d[16];
#pragma unroll
        for (int k = 0; k < 16; ++k) d[k] = csr[e + k];
#pragma unroll
        for (int k = 0; k < 16; ++k)
            a[k] = fmaf(bfval(sb, d[k], lane), wval(d[k]), a[k]);
    }
    for (; e + 3 < end; e += 4) {
        uint d[4];
#pragma unroll
        for (int k = 0; k < 4; ++k) d[k] = csr[e + k];
#pragma unroll
        for (int k = 0; k < 4; ++k)
            a[k] = fmaf(bfval(sb, d[k], lane), wval(d[k]), a[k]);
    }
    for (; e < end; ++e) {
        uint d0 = csr[e];
        a[0] = fmaf(bfval(sb, d0, lane), wval(d0), a[0]);
    }
#pragma unroll
    for (int s = 8; s; s >>= 1)
#pragma unroll
        for (int k = 0; k < s; ++k) a[k] += a[k + s];
    float hv = fmaxf(a[0] + bv, 0.f);
    if (resid) hv += resid[(size_t)wid * 64 + lane];
    out[(size_t)wid * 64 + lane] = hv;
}

// Final layer: C=40 agg over stride-64 support + bias + fused log_softmax.
__global__ __launch_bounds__(256) void agg_final_kernel(const ushort* __restrict__ sb,
                                                        const int* __restrict__ row_start,
                                                        const uint* __restrict__ csr,
                                                        const float* __restrict__ bias,
                                                        float* __restrict__ out, int n) {
    constexpr int C = 40;
    int wid = (blockIdx.x * blockDim.x + threadIdx.x) >> 6;
    int lane = threadIdx.x & 63;
    if (wid >= n) return;
    bool act = lane < C;
    int col = act ? lane : 0;
    int beg = __builtin_amdgcn_readfirstlane(row_start[wid]);
    int end = __builtin_amdgcn_readfirstlane(row_start[wid + 1]);
    float a[8];
#pragma unroll
    for (int k = 0; k < 8; ++k) a[k] = 0.f;
    int e = beg;
    for (; e + 7 < end; e += 8) {
        uint d[8];
#pragma unroll
        for (int k = 0; k < 8; ++k) d[k] = csr[e + k];
#pragma unroll
        for (int k = 0; k < 8; ++k)
            a[k] = fmaf(bfval(sb, d[k], col), wval(d[k]), a[k]);
    }
    for (; e < end; ++e) {
        uint d0 = csr[e];
        a[0] = fmaf(bfval(sb, d0, col), wval(d0), a[0]);
    }
#pragma unroll
    for (int s = 4; s; s >>= 1)
#pragma unroll
        for (int k = 0; k < s; ++k) a[k] += a[k + s];
    float v = act ? (a[0] + bias[lane]) : -INFINITY;
    float m = v;
    for (int d = 32; d; d >>= 1) m = fmaxf(m, __shfl_xor(m, d));
    float ex = act ? expf(v - m) : 0.f;
    for (int d = 32; d; d >>= 1) ex += __shfl_xor(ex, d);
    float lse = m + logf(ex);
    if (act) out[(size_t)wid * C + lane] = v - lse;
}

extern "C" void kernel_launch(void* const* d_in, const int* in_sizes, int n_in,
                              void* d_out, int out_size, void* d_ws, size_t ws_size,
                              hipStream_t stream) {
    const float* x   = (const float*)d_in[0];
    const int*   src = (const int*)d_in[1];
    const int*   tgt = (const int*)d_in[2];
    const float* mw  = (const float*)d_in[3];
    const float* W0  = (const float*)d_in[4];
    const float* b0  = (const float*)d_in[5];
    const float* W1  = (const float*)d_in[6];
    const float* b1  = (const float*)d_in[7];
    const float* W2  = (const float*)d_in[8];
    const float* b2  = (const float*)d_in[9];
    const float* W3  = (const float*)d_in[10];
    const float* b3  = (const float*)d_in[11];
    float* out = (float*)d_out;

    const int N = in_sizes[0] / 128;
    const int E = in_sizes[1];
    const int NB = (N + NB_ROWS - 1) / NB_ROWS;  // 391 buckets (<=512)

    // Workspace carve-out (~57 MB)
    char* p = (char*)d_ws;
    auto carve = [&](size_t bytes) {
        char* r = p;
        p += (bytes + 255) & ~size_t(255);
        return r;
    };
    int*    bcur      = (int*)carve((size_t)NB * 4);
    int*    bbase     = (int*)carve((size_t)NB * 4);
    int*    row_start = (int*)carve((size_t)(N + 1) * 4);
    uint*   bkt       = (uint*)carve((size_t)NB * CAP * 4);   // 7.2 MB
    uchar*  brow      = (uchar*)carve((size_t)NB * CAP);      // 1.8 MB
    uint*   csr       = (uint*)carve((size_t)E * 4);          // 6.4 MB
    ushort* support   = (ushort*)carve((size_t)N * 64 * 2);   // 12.8 MB (stride 64 all layers)
    float*  h         = (float*)carve((size_t)N * 64 * 4);    // 25.6 MB

    int gblocks = (N + 63) / 64;     // 64 nodes per block, 4 waves split cols
    int ablocks = (N + 3) / 4;       // 4 waves/block, wave per node

    // ---- CSR build ----
    zero_ints<<<(NB + 255) / 256, 256, 0, stream>>>(bcur, NB);
    bucket_kernel<<<(E + CHUNK - 1) / CHUNK, 512, 0, stream>>>(src, tgt, mw, bcur, bkt, brow, E, NB);
    bscan_kernel<<<1, 512, 0, stream>>>(bcur, bbase, row_start, NB, N);
    rowsort_kernel<<<NB, 1024, 0, stream>>>(bkt, brow, bcur, bbase, csr, row_start, N);

    // ---- Layer 0: h = relu(A @ (x @ W0) + b0) ----
    gemm_kernel<128, 64, 4, 64><<<gblocks, 256, 0, stream>>>(x, W0, (uint*)support, N);
    agg64_kernel<<<ablocks, 256, 0, stream>>>(support, row_start, csr, b0, nullptr, h, N);
    // ---- Layer 1: h = relu(A @ (h @ W1) + b1) + h ----
    gemm_kernel<64, 64, 4, 64><<<gblocks, 256, 0, stream>>>(h, W1, (uint*)support, N);
    agg64_kernel<<<ablocks, 256, 0, stream>>>(support, row_start, csr, b1, h, h, N);
    // ---- Layer 2 ----
    gemm_kernel<64, 64, 4, 64><<<gblocks, 256, 0, stream>>>(h, W2, (uint*)support, N);
    agg64_kernel<<<ablocks, 256, 0, stream>>>(support, row_start, csr, b2, h, h, N);
    // ---- Layer 3: out = log_softmax(A @ (h @ W3) + b3); support stride 64 ----
    gemm_kernel<64, 40, 4, 64><<<gblocks, 256, 0, stream>>>(h, W3, (uint*)support, N);
    agg_final_kernel<<<ablocks, 256, 0, stream>>>(support, row_start, csr, b3, out, N);
}

// Round 8
// 431.210 us; speedup vs baseline: 1.0291x; 1.0291x over previous
//
#include <hip/hip_runtime.h>
#include <cstdint>
#include <cstddef>
#include <math.h>

// RESK GCN forward: 4 graph-conv layers + residuals + log_softmax.
// R8: paired-edge gather aggregation. Wave splits: lanes 0-31 = even edges,
//     lanes 32-63 = odd edges; each lane loads a dword (2 bf16 cols) of its
//     half's edge -> one global_load_dword covers 2 edges, per-edge VALU
//     ~6 vs ~15 (R7 showed aggs are issue-bound: FETCH down 10%, dur flat,
//     VALUBusy 51%). Halves combined via shfl_xor(32); float2 epilogue.
//     CSR build + wave-split-column GEMM unchanged from R7.

typedef unsigned int uint;
typedef unsigned short ushort;
typedef unsigned char uchar;

constexpr int NB_ROWS = 256;   // rows per bucket
constexpr int CHUNK   = 2048;  // edges per bucket_kernel block
constexpr int CAP     = 4608;  // bucket window capacity (mean 4096, +8 sigma)

__device__ __forceinline__ uint f2bf(float f) {
    uint u = __float_as_uint(f);
    return (u + 0x7FFFu + ((u >> 16) & 1u)) >> 16;
}

__global__ void zero_ints(int* __restrict__ p, int n) {
    int i = blockIdx.x * blockDim.x + threadIdx.x;
    if (i < n) p[i] = 0;
}

// Stage 1: bin edges by bucket (tgt>>8) in LDS; write per-(block,bucket) runs
// contiguously. Payload = src | w15<<17 (4B) + row byte (1B side array).
__global__ __launch_bounds__(512) void bucket_kernel(const int* __restrict__ src,
                                                     const int* __restrict__ tgt,
                                                     const float* __restrict__ w,
                                                     int* __restrict__ bcur,
                                                     uint* __restrict__ bkt,
                                                     uchar* __restrict__ brow,
                                                     int E, int NB) {
    __shared__ uint binned[CHUNK];
    __shared__ ushort binb[CHUNK];
    __shared__ uchar binr[CHUNK];
    __shared__ int hist[512];
    __shared__ int sc[512];
    __shared__ int cur[512];
    __shared__ int gbase[512];
    int tid = threadIdx.x;
    int e0 = blockIdx.x * CHUNK;
    int cnt = min(CHUNK, E - e0);
    hist[tid] = 0;
    __syncthreads();
    for (int i = tid; i < cnt; i += 512) atomicAdd(&hist[tgt[e0 + i] >> 8], 1);
    __syncthreads();
    int v = hist[tid];
    sc[tid] = v;
    __syncthreads();
    for (int off = 1; off < 512; off <<= 1) {
        int t = (tid >= off) ? sc[tid - off] : 0;
        __syncthreads();
        sc[tid] += t;
        __syncthreads();
    }
    int excl = sc[tid] - v;
    if (tid < NB && v > 0) gbase[tid] = atomicAdd(&bcur[tid], v);
    __syncthreads();
    hist[tid] = excl;
    cur[tid] = excl;
    __syncthreads();
    for (int i = tid; i < cnt; i += 512) {
        int t = tgt[e0 + i];
        int b = t >> 8;
        int r = atomicAdd(&cur[b], 1);
        float wf = w[e0 + i];
        uint w15 = (uint)(int)(wf * 32767.f + 0.5f);
        if (w15 > 32767u) w15 = 32767u;
        binned[r] = (uint)src[e0 + i] | (w15 << 17);
        binb[r] = (ushort)b;
        binr[r] = (uchar)(t & 255);
    }
    __syncthreads();
    for (int i = tid; i < cnt; i += 512) {
        int b = binb[i];
        int dst = gbase[b] + (i - hist[b]);
        if (dst < CAP) {
            bkt[(size_t)b * CAP + dst] = binned[i];
            brow[(size_t)b * CAP + dst] = binr[i];
        }
    }
}

// Stage 2: exclusive scan of bucket totals -> bucket bases; total -> row_start[N].
__global__ void bscan_kernel(const int* __restrict__ bcur, int* __restrict__ bbase,
                             int* __restrict__ row_start, int NB, int N) {
    __shared__ int sd[512];
    int tid = threadIdx.x;
    int tot = (tid < NB) ? min(bcur[tid], CAP) : 0;
    sd[tid] = tot;
    __syncthreads();
    for (int off = 1; off < 512; off <<= 1) {
        int t = (tid >= off) ? sd[tid - off] : 0;
        __syncthreads();
        sd[tid] += t;
        __syncthreads();
    }
    if (tid < NB) bbase[tid] = sd[tid] - tot;
    if (tid == 511) row_start[N] = sd[511];
}

// Stage 3: per-bucket row sort -> row_start + row-sorted 4B csr entries.
__global__ __launch_bounds__(1024) void rowsort_kernel(const uint* __restrict__ bkt,
                                                       const uchar* __restrict__ brow,
                                                       const int* __restrict__ bcur,
                                                       const int* __restrict__ bbase,
                                                       uint* __restrict__ csr,
                                                       int* __restrict__ row_start, int N) {
    __shared__ int hist[256];
    __shared__ int offs[256];
    int b = blockIdx.x;
    int tid = threadIdx.x;
    int cnt = min(bcur[b], CAP);
    const uint* win = bkt + (size_t)b * CAP;
    const uchar* wrow = brow + (size_t)b * CAP;
    if (tid < 256) hist[tid] = 0;
    __syncthreads();
    uint en[5];
    uchar er[5];
    int ne = 0;
#pragma unroll
    for (int k = 0; k < 5; ++k) {
        int i = tid + k * 1024;
        if (i < cnt) {
            en[k] = win[i];
            er[k] = wrow[i];
            atomicAdd(&hist[er[k]], 1);
            ne = k + 1;
        }
    }
    __syncthreads();
    int v = 0;
    if (tid < 256) { v = hist[tid]; offs[tid] = v; }
    __syncthreads();
    for (int off = 1; off < 256; off <<= 1) {
        int t = 0;
        if (tid < 256 && tid >= off) t = offs[tid - off];
        __syncthreads();
        if (tid < 256) offs[tid] += t;
        __syncthreads();
    }
    int gb = bbase[b];
    if (tid < 256) {
        int excl = offs[tid] - v;
        int row = (b << 8) + tid;
        if (row < N) row_start[row] = gb + excl;
        hist[tid] = excl;
    }
    __syncthreads();
#pragma unroll
    for (int k = 0; k < 5; ++k) {
        if (k < ne) {
            int pos = atomicAdd(&hist[er[k]], 1);
            csr[gb + pos] = en[k];
        }
    }
}

// support = H @ W, output bf16 with row stride OS (bf16 elems). Wave-split
// columns: block = 64 nodes x WPN waves; wave cg handles C/WPN columns.
template <int K, int C, int WPN, int OS>
__global__ __launch_bounds__(64 * WPN) void gemm_kernel(const float* __restrict__ H,
                                                        const float* __restrict__ W,
                                                        uint* __restrict__ out, int n) {
    constexpr int CW = C / WPN;
    int wave = threadIdx.x >> 6;
    int lane = threadIdx.x & 63;
    int cg = __builtin_amdgcn_readfirstlane(wave);
    int node = blockIdx.x * 64 + lane;
    if (node >= n) return;
    float acc[CW];
#pragma unroll
    for (int c = 0; c < CW; ++c) acc[c] = 0.f;
    const float4* row = (const float4*)(H + (size_t)node * K);
    const float* Wg = W + cg * CW;
#pragma unroll 4
    for (int k4 = 0; k4 < K / 4; ++k4) {
        float4 xv = row[k4];
        const float* wr = Wg + (size_t)k4 * 4 * C;
#pragma unroll
        for (int c = 0; c < CW; ++c) {
            acc[c] = fmaf(xv.x, wr[c], acc[c]);
            acc[c] = fmaf(xv.y, wr[C + c], acc[c]);
            acc[c] = fmaf(xv.z, wr[2 * C + c], acc[c]);
            acc[c] = fmaf(xv.w, wr[3 * C + c], acc[c]);
        }
    }
    uint wbuf[CW / 2];
#pragma unroll
    for (int c = 0; c < CW; c += 2) wbuf[c / 2] = f2bf(acc[c]) | (f2bf(acc[c + 1]) << 16);
    uint* orow = out + (size_t)node * (OS / 2) + cg * (CW / 2);
#pragma unroll
    for (int j = 0; j < CW / 2; ++j) orow[j] = wbuf[j];
}

__device__ __forceinline__ float wval(uint d) {
    return (float)(d >> 17) * (1.0f / 32767.f);
}

// Paired-edge wave-per-node aggregation, C=64. half = lane>>5 picks
// even/odd edge of each pair; lane covers cols {2*hl, 2*hl+1} via one dword
// load. 8 pair-chains = 16 edges in flight. Masked dummy (d=0 -> w=0) lets
// one unrolled body handle any degree. out may alias resid.
__global__ __launch_bounds__(256) void agg64_kernel(const ushort* __restrict__ sb,
                                                    const int* __restrict__ row_start,
                                                    const uint* __restrict__ csr,
                                                    const float* __restrict__ bias,
                                                    const float* __restrict__ resid,
                                                    float* __restrict__ out, int n) {
    int wid = (blockIdx.x * blockDim.x + threadIdx.x) >> 6;
    int lane = threadIdx.x & 63;
    if (wid >= n) return;
    int hl = lane & 31;
    bool oddhalf = lane >= 32;
    int beg = __builtin_amdgcn_readfirstlane(row_start[wid]);
    int end = __builtin_amdgcn_readfirstlane(row_start[wid + 1]);
    float a0[8], a1[8];
#pragma unroll
    for (int k = 0; k < 8; ++k) { a0[k] = 0.f; a1[k] = 0.f; }
    for (int e = beg; e < end; e += 16) {
        uint dd[8];
#pragma unroll
        for (int k = 0; k < 8; ++k) {
            int i0 = e + 2 * k;
            uint dA = (i0 < end) ? csr[i0] : 0u;
            uint dB = (i0 + 1 < end) ? csr[i0 + 1] : 0u;
            dd[k] = oddhalf ? dB : dA;
        }
        uint uu[8];
#pragma unroll
        for (int k = 0; k < 8; ++k) {
            uint off = ((dd[k] & 0x1FFFFu) << 7) | (uint)(hl << 2);
            uu[k] = *(const uint*)((const char*)sb + off);
        }
#pragma unroll
        for (int k = 0; k < 8; ++k) {
            float wv = wval(dd[k]);
            a0[k] = fmaf(__uint_as_float(uu[k] << 16), wv, a0[k]);
            a1[k] = fmaf(__uint_as_float(uu[k] & 0xFFFF0000u), wv, a1[k]);
        }
    }
#pragma unroll
    for (int s = 4; s; s >>= 1)
#pragma unroll
        for (int k = 0; k < s; ++k) { a0[k] += a0[k + s]; a1[k] += a1[k + s]; }
    float s0 = a0[0] + __shfl_xor(a0[0], 32);
    float s1 = a1[0] + __shfl_xor(a1[0], 32);
    if (lane < 32) {
        float2 bv = *(const float2*)(bias + 2 * hl);
        float h0 = fmaxf(s0 + bv.x, 0.f);
        float h1 = fmaxf(s1 + bv.y, 0.f);
        if (resid) {
            float2 rv = *(const float2*)(resid + (size_t)wid * 64 + 2 * hl);
            h0 += rv.x;
            h1 += rv.y;
        }
        *(float2*)(out + (size_t)wid * 64 + 2 * hl) = make_float2(h0, h1);
    }
}

// Final layer: paired-edge agg over stride-64 support (cols 0..39 live) +
// bias + fused log_softmax (reductions stay within each 32-lane half).
__global__ __launch_bounds__(256) void agg_final_kernel(const ushort* __restrict__ sb,
                                                        const int* __restrict__ row_start,
                                                        const uint* __restrict__ csr,
                                                        const float* __restrict__ bias,
                                                        float* __restrict__ out, int n) {
    int wid = (blockIdx.x * blockDim.x + threadIdx.x) >> 6;
    int lane = threadIdx.x & 63;
    if (wid >= n) return;
    int hl = lane & 31;
    bool oddhalf = lane >= 32;
    int beg = __builtin_amdgcn_readfirstlane(row_start[wid]);
    int end = __builtin_amdgcn_readfirstlane(row_start[wid + 1]);
    float a0[8], a1[8];
#pragma unroll
    for (int k = 0; k < 8; ++k) { a0[k] = 0.f; a1[k] = 0.f; }
    for (int e = beg; e < end; e += 16) {
        uint dd[8];
#pragma unroll
        for (int k = 0; k < 8; ++k) {
            int i0 = e + 2 * k;
            uint dA = (i0 < end) ? csr[i0] : 0u;
            uint dB = (i0 + 1 < end) ? csr[i0 + 1] : 0u;
            dd[k] = oddhalf ? dB : dA;
        }
        uint uu[8];
#pragma unroll
        for (int k = 0; k < 8; ++k) {
            uint off = ((dd[k] & 0x1FFFFu) << 7) | (uint)(hl << 2);
            uu[k] = *(const uint*)((const char*)sb + off);
        }
#pragma unroll
        for (int k = 0; k < 8; ++k) {
            float wv = wval(dd[k]);
            a0[k] = fmaf(__uint_as_float(uu[k] << 16), wv, a0[k]);
            a1[k] = fmaf(__uint_as_float(uu[k] & 0xFFFF0000u), wv, a1[k]);
        }
    }
#pragma unroll
    for (int s = 4; s; s >>= 1)
#pragma unroll
        for (int k = 0; k < s; ++k) { a0[k] += a0[k + s]; a1[k] += a1[k + s]; }
    float s0 = a0[0] + __shfl_xor(a0[0], 32);
    float s1 = a1[0] + __shfl_xor(a1[0], 32);
    bool act = hl < 20;  // cols 2hl, 2hl+1 < 40
    float v0 = -INFINITY, v1 = -INFINITY;
    if (act) {
        float2 bv = *(const float2*)(bias + 2 * hl);
        v0 = s0 + bv.x;
        v1 = s1 + bv.y;
    }
    float m = fmaxf(v0, v1);
    for (int d = 16; d; d >>= 1) m = fmaxf(m, __shfl_xor(m, d));
    float ex = act ? (expf(v0 - m) + expf(v1 - m)) : 0.f;
    for (int d = 16; d; d >>= 1) ex += __shfl_xor(ex, d);
    float lse = m + logf(ex);
    if (act && lane < 32)
        *(float2*)(out + (size_t)wid * 40 + 2 * hl) = make_float2(v0 - lse, v1 - lse);
}

extern "C" void kernel_launch(void* const* d_in, const int* in_sizes, int n_in,
                              void* d_out, int out_size, void* d_ws, size_t ws_size,
                              hipStream_t stream) {
    const float* x   = (const float*)d_in[0];
    const int*   src = (const int*)d_in[1];
    const int*   tgt = (const int*)d_in[2];
    const float* mw  = (const float*)d_in[3];
    const float* W0  = (const float*)d_in[4];
    const float* b0  = (const float*)d_in[5];
    const float* W1  = (const float*)d_in[6];
    const float* b1  = (const float*)d_in[7];
    const float* W2  = (const float*)d_in[8];
    const float* b2  = (const float*)d_in[9];
    const float* W3  = (const float*)d_in[10];
    const float* b3  = (const float*)d_in[11];
    float* out = (float*)d_out;

    const int N = in_sizes[0] / 128;
    const int E = in_sizes[1];
    const int NB = (N + NB_ROWS - 1) / NB_ROWS;  // 391 buckets (<=512)

    // Workspace carve-out (~57 MB)
    char* p = (char*)d_ws;
    auto carve = [&](size_t bytes) {
        char* r = p;
        p += (bytes + 255) & ~size_t(255);
        return r;
    };
    int*    bcur      = (int*)carve((size_t)NB * 4);
    int*    bbase     = (int*)carve((size_t)NB * 4);
    int*    row_start = (int*)carve((size_t)(N + 1) * 4);
    uint*   bkt       = (uint*)carve((size_t)NB * CAP * 4);   // 7.2 MB
    uchar*  brow      = (uchar*)carve((size_t)NB * CAP);      // 1.8 MB
    uint*   csr       = (uint*)carve((size_t)E * 4);          // 6.4 MB
    ushort* support   = (ushort*)carve((size_t)N * 64 * 2);   // 12.8 MB (stride 64)
    float*  h         = (float*)carve((size_t)N * 64 * 4);    // 25.6 MB

    int gblocks = (N + 63) / 64;     // 64 nodes per block, 4 waves split cols
    int ablocks = (N + 3) / 4;       // 4 waves/block, wave per node

    // ---- CSR build ----
    zero_ints<<<(NB + 255) / 256, 256, 0, stream>>>(bcur, NB);
    bucket_kernel<<<(E + CHUNK - 1) / CHUNK, 512, 0, stream>>>(src, tgt, mw, bcur, bkt, brow, E, NB);
    bscan_kernel<<<1, 512, 0, stream>>>(bcur, bbase, row_start, NB, N);
    rowsort_kernel<<<NB, 1024, 0, stream>>>(bkt, brow, bcur, bbase, csr, row_start, N);

    // ---- Layer 0: h = relu(A @ (x @ W0) + b0) ----
    gemm_kernel<128, 64, 4, 64><<<gblocks, 256, 0, stream>>>(x, W0, (uint*)support, N);
    agg64_kernel<<<ablocks, 256, 0, stream>>>(support, row_start, csr, b0, nullptr, h, N);
    // ---- Layer 1: h = relu(A @ (h @ W1) + b1) + h ----
    gemm_kernel<64, 64, 4, 64><<<gblocks, 256, 0, stream>>>(h, W1, (uint*)support, N);
    agg64_kernel<<<ablocks, 256, 0, stream>>>(support, row_start, csr, b1, h, h, N);
    // ---- Layer 2 ----
    gemm_kernel<64, 64, 4, 64><<<gblocks, 256, 0, stream>>>(h, W2, (uint*)support, N);
    agg64_kernel<<<ablocks, 256, 0, stream>>>(support, row_start, csr, b2, h, h, N);
    // ---- Layer 3: out = log_softmax(A @ (h @ W3) + b3); support stride 64 ----
    gemm_kernel<64, 40, 4, 64><<<gblocks, 256, 0, stream>>>(h, W3, (uint*)support, N);
    agg_final_kernel<<<ablocks, 256, 0, stream>>>(support, row_start, csr, b3, out, N);
}